// Round 9
// baseline (178.605 us; speedup 1.0000x reference)
//
#include <hip/hip_runtime.h>

// Spatial transformer: trilinear warp of src by flow, border padding.
// D=160, H=192, W=160.  u = (idx + flow) * S/(S-1) - 0.5, clamp, trilinear.
//
// Lineage:
//   R5-R9: global-gather designs all ~50us (scattered-line service wall).
//   R10: LDS-staged 32^3 window -> 52us (latency-bound).
//   R11/R12: outlier deferral via PER-VOXEL same-line global atomicAdd
//        -> 124us: chip-wide serializer. Never on the per-element path.
//   R13: 48KB window (3 blocks/CU) + flow hoist -> 49.3us, occ 29->41%,
//        VALU 19%. In-wave outlier slow path STILL present: ~77% of
//        voxel-iters expose a ~700cyc scattered-gather chain in-wave.
// R14: single change: defer outliers via BLOCK-LOCAL LDS compaction
//   (LDS atomic append; ONE global atomicAdd per block = 2400 total;
//   coalesced flush; fixup kernel resolves ~110K voxels). Main wave
//   never waits on a scattered global load. Overflow (>256/block, p~0)
//   handled inline for correctness.

#define DD 160
#define HH 192
#define WW 160
#define DHW (DD * HH * WW)
#define PW 192                                   /* padded width: slot s <-> gx = clamp(s-8) */
#define NROWS (DD * HH)                          /* 30720 */
#define BSRC_BYTES ((size_t)NROWS * PW * 2)      /* 11,796,480 */
#define LCAP 256                                 /* per-block outlier slots */
#define GCAP (2400 * LCAP)                       /* 614,400: cannot overflow */
#define CNT_OFF BSRC_BYTES
#define LIST_OFF (BSRC_BYTES + 64)
#define WS_NEEDED (LIST_OFF + 4ULL * GCAP)

__device__ __forceinline__ unsigned short bf16_rn(float f) {
    unsigned int u = __float_as_uint(f);
    return (unsigned short)((u + 0x7FFFu + ((u >> 16) & 1u)) >> 16);
}

// ---------------- prepass: padded bf16 volume (+ zero global counter) ----------------
// bsrc[row][s] = bf16(src[row][clamp(s-8, 0, WW-1)]), s in [0,192)
__global__ __launch_bounds__(256) void pack_bf16_kernel(
    const float* __restrict__ src, unsigned short* __restrict__ bsrc,
    unsigned int* __restrict__ gcnt)
{
    if (blockIdx.x == 0 && threadIdx.x == 0) *gcnt = 0u;   // reset each replay

    int t = blockIdx.x * 256 + (int)threadIdx.x;  // 737,280 threads = 2880 blocks
    int q = t % (PW / 8);                          // 24 chunks of 8 slots
    int row = t / (PW / 8);                        // [0, 30720)
    const float* srow = src + (size_t)row * WW;
    int j0 = q * 8;

    unsigned int e[4];
    #pragma unroll
    for (int i = 0; i < 4; ++i) {
        int ga = min(max(j0 + 2 * i     - 8, 0), WW - 1);
        int gb = min(max(j0 + 2 * i + 1 - 8, 0), WW - 1);
        e[i] = (unsigned int)bf16_rn(srow[ga]) | ((unsigned int)bf16_rn(srow[gb]) << 16);
    }
    *(uint4*)(bsrc + (size_t)row * PW + j0) = make_uint4(e[0], e[1], e[2], e[3]);
}

// ---------------- main: LDS-staged trilinear, 48KB window, deferred outliers ----------------
struct __align__(4) F2 { float a, b; };

__global__ __launch_bounds__(512) void warp_lds_kernel(
    const unsigned short* __restrict__ bsrc,
    const float* __restrict__ src,
    const float* __restrict__ flow,
    float* __restrict__ out,
    unsigned int* __restrict__ gcnt,
    unsigned int* __restrict__ glist)
{
    __shared__ unsigned short sm[24 * 32 * 32];   // 48 KB: [dz<24][dy<32][dx<32]
    __shared__ unsigned int lcnt;
    __shared__ unsigned int lbase;
    __shared__ unsigned int llist[LCAP];          // 1 KB

    // grid 2400 = 10 x 12 x 20; XCD k gets contiguous nb range.
    int b = blockIdx.x;
    int nb = (b & 7) * 300 + (b >> 3);
    int txq = nb % 10;
    int rem = nb / 10;
    int tyq = rem % 12;
    int tzq = rem / 12;                           // [0,20)
    int bx = txq * 16, by = tyq * 16, bz = tzq * 8;

    int t = (int)threadIdx.x;                     // 512 threads = 8 waves
    int lane = t & 63;
    int wave = t >> 6;

    if (t == 0) lcnt = 0u;

    // ---- stage window: z in [bz-8, bz+16), y in [by-8, by+24), x slots [bx,bx+32) ----
    #pragma unroll
    for (int k = 0; k < 6; ++k) {
        int row = (wave * 6 + k) * 16 + (lane >> 2);   // 0..767 = zz*32+yy
        int zz = row >> 5;                              // [0,24)
        int yy = row & 31;
        int gz = min(max(bz - 8 + zz, 0), DD - 1);
        int gy = min(max(by - 8 + yy, 0), HH - 1);
        const uint4 vv = *(const uint4*)(bsrc + (size_t)(gz * HH + gy) * PW + bx + (lane & 3) * 8);
        *(uint4*)&sm[row * 32 + (lane & 3) * 8] = vv;
    }

    // ---- flow for this thread's 4 voxels, issued BEFORE the barrier ----
    int vi = t * 4;                               // [0,2048) = 16x16x8 tile
    int tx = vi & 15;
    int ty = (vi >> 4) & 15;
    int tz = vi >> 8;                             // [0,8)
    int gw = bx + tx, gh = by + ty, gd = bz + tz;
    int gbase = (gd * HH + gh) * WW + gw;

    const float4 fz4 = *(const float4*)(flow + gbase);            // -> D/z
    const float4 fy4 = *(const float4*)(flow + DHW + gbase);      // -> H/y
    const float4 fx4 = *(const float4*)(flow + 2 * DHW + gbase);  // -> W/x
    const float* pz = (const float*)&fz4;
    const float* py = (const float*)&fy4;
    const float* px = (const float*)&fx4;

    __syncthreads();

    const float SX = (float)WW / (float)(WW - 1);
    const float SY = (float)HH / (float)(HH - 1);
    const float SZ = (float)DD / (float)(DD - 1);

    float res[4];
    #pragma unroll
    for (int v = 0; v < 4; ++v) {
        float ux = fmaf((float)(gw + v) + px[v], SX, -0.5f);
        float uy = fmaf((float)gh + py[v],       SY, -0.5f);
        float uz = fmaf((float)gd + pz[v],       SZ, -0.5f);
        ux = fminf(fmaxf(ux, 0.0f), (float)(WW - 1));
        uy = fminf(fmaxf(uy, 0.0f), (float)(HH - 1));
        uz = fminf(fmaxf(uz, 0.0f), (float)(DD - 1));
        float x0f = floorf(ux), y0f = floorf(uy), z0f = floorf(uz);
        float wx = ux - x0f, wy = uy - y0f, wz = uz - z0f;
        int x0 = (int)x0f, y0 = (int)y0f, z0 = (int)z0f;

        int dx = x0 - bx + 8;                 // window-local coords
        int dy = y0 - by + 8;
        int dz = z0 - bz + 8;
        // need [d, d+1] in window: dx,dy <= 30; dz <= 22
        bool ok = ((unsigned)dx <= 30u) & ((unsigned)dy <= 30u) & ((unsigned)dz <= 22u);

        bool inline_slow = false;
        if (!ok) {
            unsigned int slot = atomicAdd(&lcnt, 1u);   // LDS atomic: cheap
            if (slot < LCAP) llist[slot] = (unsigned int)(gbase + v);
            else inline_slow = true;                    // p ~ 0; correctness only
            dx = min(max(dx, 0), 30);
            dy = min(max(dy, 0), 30);
            dz = min(max(dz, 0), 22);
        }

        int idx = dz * 1024 + dy * 32 + dx;   // max 23518; +1057 = 24575 < 24576
        float c000 = __uint_as_float((unsigned)sm[idx       ] << 16);
        float c001 = __uint_as_float((unsigned)sm[idx + 1   ] << 16);
        float c010 = __uint_as_float((unsigned)sm[idx + 32  ] << 16);
        float c011 = __uint_as_float((unsigned)sm[idx + 33  ] << 16);
        float c100 = __uint_as_float((unsigned)sm[idx + 1024] << 16);
        float c101 = __uint_as_float((unsigned)sm[idx + 1025] << 16);
        float c110 = __uint_as_float((unsigned)sm[idx + 1056] << 16);
        float c111 = __uint_as_float((unsigned)sm[idx + 1057] << 16);
        float r00 = fmaf(wx, c001 - c000, c000);
        float r01 = fmaf(wx, c011 - c010, c010);
        float r10 = fmaf(wx, c101 - c100, c100);
        float r11 = fmaf(wx, c111 - c110, c110);
        float r0  = fmaf(wy, r01 - r00, r00);
        float r1  = fmaf(wy, r11 - r10, r10);
        float r   = fmaf(wz, r1 - r0, r0);

        if (inline_slow) {
            // overflow fallback (never taken for N(0,3) flow): exact gather
            int y1 = min(y0 + 1, HH - 1);
            int z1 = min(z0 + 1, DD - 1);
            int xb = min(x0, WW - 2);
            bool xe = (x0 == WW - 1);
            F2 q00 = *(const F2*)(src + ((size_t)z0 * HH + y0) * WW + xb);
            F2 q01 = *(const F2*)(src + ((size_t)z0 * HH + y1) * WW + xb);
            F2 q10 = *(const F2*)(src + ((size_t)z1 * HH + y0) * WW + xb);
            F2 q11 = *(const F2*)(src + ((size_t)z1 * HH + y1) * WW + xb);
            float c000s = xe ? q00.b : q00.a, c001s = q00.b;
            float c010s = xe ? q01.b : q01.a, c011s = q01.b;
            float c100s = xe ? q10.b : q10.a, c101s = q10.b;
            float c110s = xe ? q11.b : q11.a, c111s = q11.b;
            float s00 = fmaf(wx, c001s - c000s, c000s);
            float s01 = fmaf(wx, c011s - c010s, c010s);
            float s10 = fmaf(wx, c101s - c100s, c100s);
            float s11 = fmaf(wx, c111s - c110s, c110s);
            float s0  = fmaf(wy, s01 - s00, s00);
            float s1  = fmaf(wy, s11 - s10, s10);
            r = fmaf(wz, s1 - s0, s0);
        }
        res[v] = r;
    }
    *(float4*)(out + gbase) = make_float4(res[0], res[1], res[2], res[3]);

    // ---- flush block outlier list: ONE global atomic per block ----
    __syncthreads();
    unsigned int total = min(lcnt, (unsigned int)LCAP);
    if (t == 0 && total > 0) lbase = atomicAdd(gcnt, total);
    __syncthreads();
    for (unsigned int i = t; i < total; i += 512)
        glist[lbase + i] = llist[i];
}

// ---------------- fixup: exact f32 border gather for listed outliers ----------------
__global__ __launch_bounds__(256) void fixup_kernel(
    const float* __restrict__ src,
    const float* __restrict__ flow,
    float* __restrict__ out,
    const unsigned int* __restrict__ gcnt,
    const unsigned int* __restrict__ glist)
{
    unsigned int n = min(*gcnt, (unsigned int)GCAP);
    const float SX = (float)WW / (float)(WW - 1);
    const float SY = (float)HH / (float)(HH - 1);
    const float SZ = (float)DD / (float)(DD - 1);

    for (unsigned int t = blockIdx.x * 256 + threadIdx.x; t < n; t += 512 * 256) {
        int id = (int)glist[t];
        int w = id % WW;
        int tmp = id / WW;
        int h = tmp % HH;
        int d = tmp / HH;

        float flz = flow[id];
        float fly = flow[DHW + id];
        float flx = flow[2 * DHW + id];

        float ux = fmaf((float)w + flx, SX, -0.5f);
        float uy = fmaf((float)h + fly, SY, -0.5f);
        float uz = fmaf((float)d + flz, SZ, -0.5f);
        ux = fminf(fmaxf(ux, 0.0f), (float)(WW - 1));
        uy = fminf(fmaxf(uy, 0.0f), (float)(HH - 1));
        uz = fminf(fmaxf(uz, 0.0f), (float)(DD - 1));
        float x0f = floorf(ux), y0f = floorf(uy), z0f = floorf(uz);
        float fx = ux - x0f, fy = uy - y0f, fz = uz - z0f;
        int x0 = (int)x0f, y0 = (int)y0f, z0 = (int)z0f;
        int y1 = min(y0 + 1, HH - 1);
        int z1 = min(z0 + 1, DD - 1);
        int xb = min(x0, WW - 2);
        bool xe = (x0 == WW - 1);
        F2 q00 = *(const F2*)(src + ((size_t)z0 * HH + y0) * WW + xb);
        F2 q01 = *(const F2*)(src + ((size_t)z0 * HH + y1) * WW + xb);
        F2 q10 = *(const F2*)(src + ((size_t)z1 * HH + y0) * WW + xb);
        F2 q11 = *(const F2*)(src + ((size_t)z1 * HH + y1) * WW + xb);
        float c000 = xe ? q00.b : q00.a, c001 = q00.b;
        float c010 = xe ? q01.b : q01.a, c011 = q01.b;
        float c100 = xe ? q10.b : q10.a, c101 = q10.b;
        float c110 = xe ? q11.b : q11.a, c111 = q11.b;
        float r00 = fmaf(fx, c001 - c000, c000);
        float r01 = fmaf(fx, c011 - c010, c010);
        float r10 = fmaf(fx, c101 - c100, c100);
        float r11 = fmaf(fx, c111 - c110, c110);
        float r0  = fmaf(fy, r01 - r00, r00);
        float r1  = fmaf(fy, r11 - r10, r10);
        out[id] = fmaf(fz, r1 - r0, r0);
    }
}

// ---------------- fallback (proven R2 kernel) if ws too small ----------------
__global__ __launch_bounds__(256) void warp_direct_kernel(
    const float* __restrict__ src,
    const float* __restrict__ flow,
    float* __restrict__ out)
{
    int b = blockIdx.x;
    int nb = (b & 7) * 600 + (b >> 3);
    int base = (nb * 256 + (int)threadIdx.x) * 4;

    int w = base % WW;
    int tmp = base / WW;
    int h = tmp % HH;
    int d = tmp / HH;

    const float4 f0  = *(const float4*)(flow + base);
    const float4 f1  = *(const float4*)(flow + DHW + base);
    const float4 f2v = *(const float4*)(flow + 2 * DHW + base);
    const float* f0p = (const float*)&f0;
    const float* f1p = (const float*)&f1;
    const float* f2p = (const float*)&f2v;

    const float SX = (float)WW / (float)(WW - 1);
    const float SY = (float)HH / (float)(HH - 1);
    const float SZ = (float)DD / (float)(DD - 1);

    float res[4];
    #pragma unroll
    for (int v = 0; v < 4; ++v) {
        float ux = fmaf((float)(w + v) + f2p[v], SX, -0.5f);
        float uy = fmaf((float)h + f1p[v],       SY, -0.5f);
        float uz = fmaf((float)d + f0p[v],       SZ, -0.5f);
        ux = fminf(fmaxf(ux, 0.0f), (float)(WW - 1));
        uy = fminf(fmaxf(uy, 0.0f), (float)(HH - 1));
        uz = fminf(fmaxf(uz, 0.0f), (float)(DD - 1));
        float x0f = floorf(ux), y0f = floorf(uy), z0f = floorf(uz);
        float fx = ux - x0f, fy = uy - y0f, fz = uz - z0f;
        int x0 = (int)x0f, y0 = (int)y0f, z0 = (int)z0f;
        int y1 = min(y0 + 1, HH - 1);
        int z1 = min(z0 + 1, DD - 1);
        int xb = min(x0, WW - 2);
        bool xe = (x0 == WW - 1);
        F2 q00 = *(const F2*)(src + ((size_t)z0 * HH + y0) * WW + xb);
        F2 q01 = *(const F2*)(src + ((size_t)z0 * HH + y1) * WW + xb);
        F2 q10 = *(const F2*)(src + ((size_t)z1 * HH + y0) * WW + xb);
        F2 q11 = *(const F2*)(src + ((size_t)z1 * HH + y1) * WW + xb);
        float c000 = xe ? q00.b : q00.a, c001 = q00.b;
        float c010 = xe ? q01.b : q01.a, c011 = q01.b;
        float c100 = xe ? q10.b : q10.a, c101 = q10.b;
        float c110 = xe ? q11.b : q11.a, c111 = q11.b;
        float r00 = fmaf(fx, c001 - c000, c000);
        float r01 = fmaf(fx, c011 - c010, c010);
        float r10 = fmaf(fx, c101 - c100, c100);
        float r11 = fmaf(fx, c111 - c110, c110);
        float r0  = fmaf(fy, r01 - r00, r00);
        float r1  = fmaf(fy, r11 - r10, r10);
        res[v]    = fmaf(fz, r1 - r0, r0);
    }
    *(float4*)(out + base) = make_float4(res[0], res[1], res[2], res[3]);
}

extern "C" void kernel_launch(void* const* d_in, const int* in_sizes, int n_in,
                              void* d_out, int out_size, void* d_ws, size_t ws_size,
                              hipStream_t stream) {
    const float* src  = (const float*)d_in[0];   // [1,1,D,H,W]
    const float* flow = (const float*)d_in[1];   // [1,3,D,H,W]
    // d_in[2] identity grid: unused (recomputed)
    float* out = (float*)d_out;

    if (ws_size >= WS_NEEDED) {
        unsigned short* bsrc = (unsigned short*)d_ws;
        unsigned int* gcnt  = (unsigned int*)((char*)d_ws + CNT_OFF);
        unsigned int* glist = (unsigned int*)((char*)d_ws + LIST_OFF);
        pack_bf16_kernel<<<(NROWS * (PW / 8)) / 256, 256, 0, stream>>>(src, bsrc, gcnt);
        warp_lds_kernel<<<2400, 512, 0, stream>>>(bsrc, src, flow, out, gcnt, glist);
        fixup_kernel<<<512, 256, 0, stream>>>(src, flow, out, gcnt, glist);
    } else {
        warp_direct_kernel<<<DHW / 4 / 256, 256, 0, stream>>>(src, flow, out);
    }
}

// Round 10
// 175.718 us; speedup vs baseline: 1.0164x; 1.0164x over previous
//
#include <hip/hip_runtime.h>

// Spatial transformer: trilinear warp of src by flow, border padding.
// D=160, H=192, W=160.  u = (idx + flow) * S/(S-1) - 0.5, clamp, trilinear.
//
// Lineage:
//   R5-R9: global-gather designs ~50us (scattered-line service wall,
//          4.9M lines x ~6cyc/line / 256CU / 2.4GHz ~ 48us).
//   R10-R14: LDS-staged family converges 48.5-52us. R14 counters: no pipe
//          >19%, kernel at ~5x its pipe-sum floor => exposed latency from
//          2400 block cold-starts (stage 48KB + flow HBM round-trip each),
//          ~9.4 serial per CU. Occupancy/ILP/slow-path levers all ~null.
// R15: persistent z-walking blocks. Block owns a 16x16 (x,y) column, walks
//   5 z-tiles via a 24-deep circular z-window (53KB LDS). Per step: restage
//   only 8 new planes (16KB) with rows PREFETCHED TO REGS during the
//   previous step's compute (T14 async split); flow for step s+1 likewise.
//   480 blocks all co-resident (<=3/CU) => one cold start per block.
//   Outlier deferral: R14's LDS compaction (LCAP 1024 for 5 steps).

#define DD 160
#define HH 192
#define WW 160
#define DHW (DD * HH * WW)
#define PW 192                                   /* padded width: slot s <-> gx = clamp(s-8) */
#define NROWS (DD * HH)                          /* 30720 */
#define BSRC_BYTES ((size_t)NROWS * PW * 2)      /* 11,796,480 */
#define LCAP 1024                                /* per-block outlier slots (5 steps) */
#define NBLK 480
#define GCAP (NBLK * LCAP)                       /* 491,520: cannot overflow */
#define CNT_OFF BSRC_BYTES
#define LIST_OFF (BSRC_BYTES + 64)
#define WS_NEEDED (LIST_OFF + 4ULL * GCAP)

__device__ __forceinline__ unsigned short bf16_rn(float f) {
    unsigned int u = __float_as_uint(f);
    return (unsigned short)((u + 0x7FFFu + ((u >> 16) & 1u)) >> 16);
}

// ---------------- prepass: padded bf16 volume (+ zero global counter) ----------------
// bsrc[row][s] = bf16(src[row][clamp(s-8, 0, WW-1)]), s in [0,192)
__global__ __launch_bounds__(256) void pack_bf16_kernel(
    const float* __restrict__ src, unsigned short* __restrict__ bsrc,
    unsigned int* __restrict__ gcnt)
{
    if (blockIdx.x == 0 && threadIdx.x == 0) *gcnt = 0u;   // reset each replay

    int t = blockIdx.x * 256 + (int)threadIdx.x;  // 737,280 threads = 2880 blocks
    int q = t % (PW / 8);                          // 24 chunks of 8 slots
    int row = t / (PW / 8);                        // [0, 30720)
    const float* srow = src + (size_t)row * WW;
    int j0 = q * 8;

    unsigned int e[4];
    #pragma unroll
    for (int i = 0; i < 4; ++i) {
        int ga = min(max(j0 + 2 * i     - 8, 0), WW - 1);
        int gb = min(max(j0 + 2 * i + 1 - 8, 0), WW - 1);
        e[i] = (unsigned int)bf16_rn(srow[ga]) | ((unsigned int)bf16_rn(srow[gb]) << 16);
    }
    *(uint4*)(bsrc + (size_t)row * PW + j0) = make_uint4(e[0], e[1], e[2], e[3]);
}

// ---------------- main: persistent z-walk, circular 24-plane LDS window ----------------
struct __align__(4) F2 { float a, b; };

__global__ __launch_bounds__(512) void warp_walk_kernel(
    const unsigned short* __restrict__ bsrc,
    const float* __restrict__ src,
    const float* __restrict__ flow,
    float* __restrict__ out,
    unsigned int* __restrict__ gcnt,
    unsigned int* __restrict__ glist)
{
    __shared__ unsigned short sm[24 * 32 * 32];   // 48 KB circular: [slot<24][dy<32][dx<32]
    __shared__ unsigned int lcnt;
    __shared__ unsigned int lbase;
    __shared__ unsigned int llist[LCAP];          // 4 KB

    // grid 480 = 8 x 60; XCD k gets contiguous nb range.
    int b = blockIdx.x;
    int nb = (b & 7) * 60 + (b >> 3);
    int txq = nb % 10;
    int rem = nb / 10;                            // [0,48)
    int tyq = rem % 12;
    int zq  = rem / 12;                           // [0,4): z-quarter of 40
    int bx = txq * 16, by = tyq * 16;
    int bz0 = zq * 40;

    int t = (int)threadIdx.x;                     // 512 threads = 8 waves
    int lane = t & 63;
    int wave = t >> 6;
    if (t == 0) lcnt = 0u;

    // ---- cold stage: planes g in [bz0-8, bz0+16) at slot (g mod 24) ----
    int cold_wb = (16 * zq + 16) % 24;            // (bz0-8) mod 24
    #pragma unroll
    for (int k = 0; k < 6; ++k) {
        int row = (wave * 6 + k) * 16 + (lane >> 2);   // 0..767
        int j  = row >> 5;                              // plane idx [0,24)
        int yy = row & 31;
        int slot = cold_wb + j; if (slot >= 24) slot -= 24;
        int gz = min(max(bz0 - 8 + j, 0), DD - 1);
        int gy = min(max(by - 8 + yy, 0), HH - 1);
        const uint4 vv = *(const uint4*)(bsrc + (size_t)(gz * HH + gy) * PW + bx + (lane & 3) * 8);
        *(uint4*)&sm[(slot * 32 + yy) * 32 + (lane & 3) * 8] = vv;
    }

    // ---- fixed (x,y) voxel coords; z walks in 8-steps ----
    int vi = t * 4;
    int tx = vi & 15, ty = (vi >> 4) & 15, tz = vi >> 8;  // tz in [0,8)
    int gw = bx + tx, gh = by + ty;

    // flow for step 0 (latency hides under cold stage)
    int gb0 = ((bz0 + tz) * HH + gh) * WW + gw;
    float4 fzc = *(const float4*)(flow + gb0);
    float4 fyc = *(const float4*)(flow + DHW + gb0);
    float4 fxc = *(const float4*)(flow + 2 * DHW + gb0);

    __syncthreads();

    const float SX = (float)WW / (float)(WW - 1);
    const float SY = (float)HH / (float)(HH - 1);
    const float SZ = (float)DD / (float)(DD - 1);

    #pragma unroll
    for (int s = 0; s < 5; ++s) {
        int bz = bz0 + 8 * s;
        int wb = (16 * zq + 8 * s + 16) % 24;     // (bz-8) mod 24 == (bz+16) mod 24
        int gb = ((bz + tz) * HH + gh) * WW + gw;

        // ---- prefetch next step: flow + 8 restage planes -> REGS (T14) ----
        float4 nfz, nfy, nfx;
        uint4 rg0, rg1;
        if (s < 4) {
            int gbn = gb + 8 * HH * WW;
            nfz = *(const float4*)(flow + gbn);
            nfy = *(const float4*)(flow + DHW + gbn);
            nfx = *(const float4*)(flow + 2 * DHW + gbn);
            // restage rows: plane j = wave (8 planes), yy = k*16 + lane/4
            {
                int g = bz + 16 + wave;
                int gz = min(g, DD - 1);
                int yy0 = (lane >> 2);
                int gy0 = min(max(by - 8 + yy0, 0), HH - 1);
                rg0 = *(const uint4*)(bsrc + (size_t)(gz * HH + gy0) * PW + bx + (lane & 3) * 8);
                int yy1 = 16 + (lane >> 2);
                int gy1 = min(max(by - 8 + yy1, 0), HH - 1);
                rg1 = *(const uint4*)(bsrc + (size_t)(gz * HH + gy1) * PW + bx + (lane & 3) * 8);
            }
        }

        // ---- compute 4 voxels from the current window ----
        const float* pz = (const float*)&fzc;
        const float* py = (const float*)&fyc;
        const float* px = (const float*)&fxc;
        int gd = bz + tz;

        float res[4];
        #pragma unroll
        for (int v = 0; v < 4; ++v) {
            float ux = fmaf((float)(gw + v) + px[v], SX, -0.5f);
            float uy = fmaf((float)gh + py[v],       SY, -0.5f);
            float uz = fmaf((float)gd + pz[v],       SZ, -0.5f);
            ux = fminf(fmaxf(ux, 0.0f), (float)(WW - 1));
            uy = fminf(fmaxf(uy, 0.0f), (float)(HH - 1));
            uz = fminf(fmaxf(uz, 0.0f), (float)(DD - 1));
            float x0f = floorf(ux), y0f = floorf(uy), z0f = floorf(uz);
            float wx = ux - x0f, wy = uy - y0f, wz = uz - z0f;
            int x0 = (int)x0f, y0 = (int)y0f, z0 = (int)z0f;

            int dx = x0 - bx + 8;
            int dy = y0 - by + 8;
            int dz = z0 - bz + 8;
            bool ok = ((unsigned)dx <= 30u) & ((unsigned)dy <= 30u) & ((unsigned)dz <= 22u);

            bool inline_slow = false;
            if (!ok) {
                unsigned int slot = atomicAdd(&lcnt, 1u);   // LDS atomic: cheap
                if (slot < LCAP) llist[slot] = (unsigned int)(gb + v);
                else inline_slow = true;                    // p ~ 0; correctness only
                dx = min(max(dx, 0), 30);
                dy = min(max(dy, 0), 30);
                dz = min(max(dz, 0), 22);
            }

            int s0 = wb + dz; if (s0 >= 24) s0 -= 24;       // slot of plane z0
            int s1 = s0 + 1;  if (s1 >= 24) s1 -= 24;       // slot of plane z0+1
            int ia = s0 * 1024 + dy * 32 + dx;              // <= 24543 < 24576
            int ib = s1 * 1024 + dy * 32 + dx;
            float c000 = __uint_as_float((unsigned)sm[ia     ] << 16);
            float c001 = __uint_as_float((unsigned)sm[ia + 1 ] << 16);
            float c010 = __uint_as_float((unsigned)sm[ia + 32] << 16);
            float c011 = __uint_as_float((unsigned)sm[ia + 33] << 16);
            float c100 = __uint_as_float((unsigned)sm[ib     ] << 16);
            float c101 = __uint_as_float((unsigned)sm[ib + 1 ] << 16);
            float c110 = __uint_as_float((unsigned)sm[ib + 32] << 16);
            float c111 = __uint_as_float((unsigned)sm[ib + 33] << 16);
            float r00 = fmaf(wx, c001 - c000, c000);
            float r01 = fmaf(wx, c011 - c010, c010);
            float r10 = fmaf(wx, c101 - c100, c100);
            float r11 = fmaf(wx, c111 - c110, c110);
            float r0  = fmaf(wy, r01 - r00, r00);
            float r1  = fmaf(wy, r11 - r10, r10);
            float r   = fmaf(wz, r1 - r0, r0);

            if (inline_slow) {
                // overflow fallback (never taken for N(0,3) flow): exact gather
                int y1 = min(y0 + 1, HH - 1);
                int z1 = min(z0 + 1, DD - 1);
                int xb = min(x0, WW - 2);
                bool xe = (x0 == WW - 1);
                F2 q00 = *(const F2*)(src + ((size_t)z0 * HH + y0) * WW + xb);
                F2 q01 = *(const F2*)(src + ((size_t)z0 * HH + y1) * WW + xb);
                F2 q10 = *(const F2*)(src + ((size_t)z1 * HH + y0) * WW + xb);
                F2 q11 = *(const F2*)(src + ((size_t)z1 * HH + y1) * WW + xb);
                float c000s = xe ? q00.b : q00.a, c001s = q00.b;
                float c010s = xe ? q01.b : q01.a, c011s = q01.b;
                float c100s = xe ? q10.b : q10.a, c101s = q10.b;
                float c110s = xe ? q11.b : q11.a, c111s = q11.b;
                float u00 = fmaf(wx, c001s - c000s, c000s);
                float u01 = fmaf(wx, c011s - c010s, c010s);
                float u10 = fmaf(wx, c101s - c100s, c100s);
                float u11 = fmaf(wx, c111s - c110s, c110s);
                float u0  = fmaf(wy, u01 - u00, u00);
                float u1  = fmaf(wy, u11 - u10, u10);
                r = fmaf(wz, u1 - u0, u0);
            }
            res[v] = r;
        }
        *(float4*)(out + gb) = make_float4(res[0], res[1], res[2], res[3]);

        // ---- slide window: write prefetched planes, swap flow regs ----
        if (s < 4) {
            __syncthreads();                       // everyone done reading retiring planes
            {
                int slot = wb + wave; if (slot >= 24) slot -= 24;   // (bz+16+wave) mod 24
                int yy0 = (lane >> 2);
                *(uint4*)&sm[(slot * 32 + yy0) * 32 + (lane & 3) * 8] = rg0;
                int yy1 = 16 + (lane >> 2);
                *(uint4*)&sm[(slot * 32 + yy1) * 32 + (lane & 3) * 8] = rg1;
            }
            __syncthreads();                       // new planes visible
            fzc = nfz; fyc = nfy; fxc = nfx;
        }
    }

    // ---- flush block outlier list: ONE global atomic per block ----
    __syncthreads();
    unsigned int total = min(lcnt, (unsigned int)LCAP);
    if (t == 0 && total > 0) lbase = atomicAdd(gcnt, total);
    __syncthreads();
    for (unsigned int i = t; i < total; i += 512)
        glist[lbase + i] = llist[i];
}

// ---------------- fixup: exact f32 border gather for listed outliers ----------------
__global__ __launch_bounds__(256) void fixup_kernel(
    const float* __restrict__ src,
    const float* __restrict__ flow,
    float* __restrict__ out,
    const unsigned int* __restrict__ gcnt,
    const unsigned int* __restrict__ glist)
{
    unsigned int n = min(*gcnt, (unsigned int)GCAP);
    const float SX = (float)WW / (float)(WW - 1);
    const float SY = (float)HH / (float)(HH - 1);
    const float SZ = (float)DD / (float)(DD - 1);

    for (unsigned int t = blockIdx.x * 256 + threadIdx.x; t < n; t += 512 * 256) {
        int id = (int)glist[t];
        int w = id % WW;
        int tmp = id / WW;
        int h = tmp % HH;
        int d = tmp / HH;

        float flz = flow[id];
        float fly = flow[DHW + id];
        float flx = flow[2 * DHW + id];

        float ux = fmaf((float)w + flx, SX, -0.5f);
        float uy = fmaf((float)h + fly, SY, -0.5f);
        float uz = fmaf((float)d + flz, SZ, -0.5f);
        ux = fminf(fmaxf(ux, 0.0f), (float)(WW - 1));
        uy = fminf(fmaxf(uy, 0.0f), (float)(HH - 1));
        uz = fminf(fmaxf(uz, 0.0f), (float)(DD - 1));
        float x0f = floorf(ux), y0f = floorf(uy), z0f = floorf(uz);
        float fx = ux - x0f, fy = uy - y0f, fz = uz - z0f;
        int x0 = (int)x0f, y0 = (int)y0f, z0 = (int)z0f;
        int y1 = min(y0 + 1, HH - 1);
        int z1 = min(z0 + 1, DD - 1);
        int xb = min(x0, WW - 2);
        bool xe = (x0 == WW - 1);
        F2 q00 = *(const F2*)(src + ((size_t)z0 * HH + y0) * WW + xb);
        F2 q01 = *(const F2*)(src + ((size_t)z0 * HH + y1) * WW + xb);
        F2 q10 = *(const F2*)(src + ((size_t)z1 * HH + y0) * WW + xb);
        F2 q11 = *(const F2*)(src + ((size_t)z1 * HH + y1) * WW + xb);
        float c000 = xe ? q00.b : q00.a, c001 = q00.b;
        float c010 = xe ? q01.b : q01.a, c011 = q01.b;
        float c100 = xe ? q10.b : q10.a, c101 = q10.b;
        float c110 = xe ? q11.b : q11.a, c111 = q11.b;
        float r00 = fmaf(fx, c001 - c000, c000);
        float r01 = fmaf(fx, c011 - c010, c010);
        float r10 = fmaf(fx, c101 - c100, c100);
        float r11 = fmaf(fx, c111 - c110, c110);
        float r0  = fmaf(fy, r01 - r00, r00);
        float r1  = fmaf(fy, r11 - r10, r10);
        out[id] = fmaf(fz, r1 - r0, r0);
    }
}

// ---------------- fallback (proven R2 kernel) if ws too small ----------------
__global__ __launch_bounds__(256) void warp_direct_kernel(
    const float* __restrict__ src,
    const float* __restrict__ flow,
    float* __restrict__ out)
{
    int b = blockIdx.x;
    int nb = (b & 7) * 600 + (b >> 3);
    int base = (nb * 256 + (int)threadIdx.x) * 4;

    int w = base % WW;
    int tmp = base / WW;
    int h = tmp % HH;
    int d = tmp / HH;

    const float4 f0  = *(const float4*)(flow + base);
    const float4 f1  = *(const float4*)(flow + DHW + base);
    const float4 f2v = *(const float4*)(flow + 2 * DHW + base);
    const float* f0p = (const float*)&f0;
    const float* f1p = (const float*)&f1;
    const float* f2p = (const float*)&f2v;

    const float SX = (float)WW / (float)(WW - 1);
    const float SY = (float)HH / (float)(HH - 1);
    const float SZ = (float)DD / (float)(DD - 1);

    float res[4];
    #pragma unroll
    for (int v = 0; v < 4; ++v) {
        float ux = fmaf((float)(w + v) + f2p[v], SX, -0.5f);
        float uy = fmaf((float)h + f1p[v],       SY, -0.5f);
        float uz = fmaf((float)d + f0p[v],       SZ, -0.5f);
        ux = fminf(fmaxf(ux, 0.0f), (float)(WW - 1));
        uy = fminf(fmaxf(uy, 0.0f), (float)(HH - 1));
        uz = fminf(fmaxf(uz, 0.0f), (float)(DD - 1));
        float x0f = floorf(ux), y0f = floorf(uy), z0f = floorf(uz);
        float fx = ux - x0f, fy = uy - y0f, fz = uz - z0f;
        int x0 = (int)x0f, y0 = (int)y0f, z0 = (int)z0f;
        int y1 = min(y0 + 1, HH - 1);
        int z1 = min(z0 + 1, DD - 1);
        int xb = min(x0, WW - 2);
        bool xe = (x0 == WW - 1);
        F2 q00 = *(const F2*)(src + ((size_t)z0 * HH + y0) * WW + xb);
        F2 q01 = *(const F2*)(src + ((size_t)z0 * HH + y1) * WW + xb);
        F2 q10 = *(const F2*)(src + ((size_t)z1 * HH + y0) * WW + xb);
        F2 q11 = *(const F2*)(src + ((size_t)z1 * HH + y1) * WW + xb);
        float c000 = xe ? q00.b : q00.a, c001 = q00.b;
        float c010 = xe ? q01.b : q01.a, c011 = q01.b;
        float c100 = xe ? q10.b : q10.a, c101 = q10.b;
        float c110 = xe ? q11.b : q11.a, c111 = q11.b;
        float r00 = fmaf(fx, c001 - c000, c000);
        float r01 = fmaf(fx, c011 - c010, c010);
        float r10 = fmaf(fx, c101 - c100, c100);
        float r11 = fmaf(fx, c111 - c110, c110);
        float r0  = fmaf(fy, r01 - r00, r00);
        float r1  = fmaf(fy, r11 - r10, r10);
        res[v]    = fmaf(fz, r1 - r0, r0);
    }
    *(float4*)(out + base) = make_float4(res[0], res[1], res[2], res[3]);
}

extern "C" void kernel_launch(void* const* d_in, const int* in_sizes, int n_in,
                              void* d_out, int out_size, void* d_ws, size_t ws_size,
                              hipStream_t stream) {
    const float* src  = (const float*)d_in[0];   // [1,1,D,H,W]
    const float* flow = (const float*)d_in[1];   // [1,3,D,H,W]
    // d_in[2] identity grid: unused (recomputed)
    float* out = (float*)d_out;

    if (ws_size >= WS_NEEDED) {
        unsigned short* bsrc = (unsigned short*)d_ws;
        unsigned int* gcnt  = (unsigned int*)((char*)d_ws + CNT_OFF);
        unsigned int* glist = (unsigned int*)((char*)d_ws + LIST_OFF);
        pack_bf16_kernel<<<(NROWS * (PW / 8)) / 256, 256, 0, stream>>>(src, bsrc, gcnt);
        warp_walk_kernel<<<NBLK, 512, 0, stream>>>(bsrc, src, flow, out, gcnt, glist);
        fixup_kernel<<<512, 256, 0, stream>>>(src, flow, out, gcnt, glist);
    } else {
        warp_direct_kernel<<<DHW / 4 / 256, 256, 0, stream>>>(src, flow, out);
    }
}

// Round 11
// 174.797 us; speedup vs baseline: 1.0218x; 1.0053x over previous
//
#include <hip/hip_runtime.h>

// Spatial transformer: trilinear warp of src by flow, border padding.
// D=160, H=192, W=160.  u = (idx + flow) * S/(S-1) - 0.5, clamp, trilinear.
//
// Lineage:
//   R5-R9 (global gather) and R10-R15 (LDS-staged: occupancy, slow-path,
//   cold-start, prefetch variants) ALL converge 48.5-52us warp time with
//   no counter >20% => structural latency floor for this op shape; stop
//   optimizing the warp kernel.
//   Total = warp + pack(~7us) + fixed(~115us). R13 (fewest passes) = best
//   total 172.8. R14's fixup machinery: +6us total for -0.6 warp (dropped).
// R16: fuse pack into staging -> ONE kernel, zero workspace. Stage from f32
//   src, convert in-register via v_cvt_pk_bf16_f32 (RNE, matches bf16_rn).
//   X-halo clamp handled by scalar-clamped lane path (edge blocks only).
//   Compute structure = R13 verbatim (proven 48.7us).

#define DD 160
#define HH 192
#define WW 160
#define DHW (DD * HH * WW)

struct __align__(4) F2 { float a, b; };

__global__ __launch_bounds__(512) void warp_fused_kernel(
    const float* __restrict__ src,
    const float* __restrict__ flow,
    float* __restrict__ out)
{
    __shared__ unsigned short sm[24 * 32 * 32];   // 48 KB: [dz<24][dy<32][dx<32]

    // grid 2400 = 10 x 12 x 20; XCD k gets contiguous nb range (its src/flow
    // slab stays L2-warm).
    int b = blockIdx.x;
    int nb = (b & 7) * 300 + (b >> 3);
    int txq = nb % 10;
    int rem = nb / 10;
    int tyq = rem % 12;
    int tzq = rem / 12;                           // [0,20)
    int bx = txq * 16, by = tyq * 16, bz = tzq * 8;

    int t = (int)threadIdx.x;                     // 512 threads = 8 waves
    int lane = t & 63;
    int wave = t >> 6;

    // ---- stage window from f32 src with in-register bf16 conversion ----
    // 768 rows (z in [bz-8,bz+16), y in [by-8,by+24)) x 32 x-slots.
    // Lane L: row = group*16 + L/4, chunk = L&3 (8 floats -> 8 bf16 = 16B).
    // Interior chunks: 2x float4 vector loads (32B-aligned). Edge chunks
    // (txq==0 chunk0 / txq==9 chunk3): per-element clamped scalar loads.
    int gx0 = bx - 8 + (lane & 3) * 8;
    bool interior = (gx0 >= 0) && (gx0 + 8 <= WW);

    #pragma unroll
    for (int k = 0; k < 6; ++k) {
        int row = (wave * 6 + k) * 16 + (lane >> 2);   // 0..767 = zz*32+yy
        int zz = row >> 5;                              // [0,24)
        int yy = row & 31;
        int gz = min(max(bz - 8 + zz, 0), DD - 1);
        int gy = min(max(by - 8 + yy, 0), HH - 1);
        const float* srow = src + (size_t)(gz * HH + gy) * WW;

        float f[8];
        if (interior) {
            float4 a = *(const float4*)(srow + gx0);
            float4 c = *(const float4*)(srow + gx0 + 4);
            f[0] = a.x; f[1] = a.y; f[2] = a.z; f[3] = a.w;
            f[4] = c.x; f[5] = c.y; f[6] = c.z; f[7] = c.w;
        } else {
            #pragma unroll
            for (int i = 0; i < 8; ++i)
                f[i] = srow[min(max(gx0 + i, 0), WW - 1)];
        }
        unsigned int e[4];
        #pragma unroll
        for (int j = 0; j < 4; ++j)
            asm("v_cvt_pk_bf16_f32 %0, %1, %2"
                : "=v"(e[j]) : "v"(f[2 * j]), "v"(f[2 * j + 1]));
        *(uint4*)&sm[row * 32 + (lane & 3) * 8] = make_uint4(e[0], e[1], e[2], e[3]);
    }

    // ---- flow for this thread's 4 voxels, issued BEFORE the barrier ----
    int vi = t * 4;                               // [0,2048) = 16x16x8 tile
    int tx = vi & 15;
    int ty = (vi >> 4) & 15;
    int tz = vi >> 8;                             // [0,8)
    int gw = bx + tx, gh = by + ty, gd = bz + tz;
    int gbase = (gd * HH + gh) * WW + gw;

    const float4 fz4 = *(const float4*)(flow + gbase);            // -> D/z
    const float4 fy4 = *(const float4*)(flow + DHW + gbase);      // -> H/y
    const float4 fx4 = *(const float4*)(flow + 2 * DHW + gbase);  // -> W/x
    const float* pz = (const float*)&fz4;
    const float* py = (const float*)&fy4;
    const float* px = (const float*)&fx4;

    __syncthreads();

    const float SX = (float)WW / (float)(WW - 1);
    const float SY = (float)HH / (float)(HH - 1);
    const float SZ = (float)DD / (float)(DD - 1);

    float res[4];
    #pragma unroll
    for (int v = 0; v < 4; ++v) {
        float ux = fmaf((float)(gw + v) + px[v], SX, -0.5f);
        float uy = fmaf((float)gh + py[v],       SY, -0.5f);
        float uz = fmaf((float)gd + pz[v],       SZ, -0.5f);
        ux = fminf(fmaxf(ux, 0.0f), (float)(WW - 1));
        uy = fminf(fmaxf(uy, 0.0f), (float)(HH - 1));
        uz = fminf(fmaxf(uz, 0.0f), (float)(DD - 1));
        float x0f = floorf(ux), y0f = floorf(uy), z0f = floorf(uz);
        float wx = ux - x0f, wy = uy - y0f, wz = uz - z0f;
        int x0 = (int)x0f, y0 = (int)y0f, z0 = (int)z0f;

        int dx = x0 - bx + 8;                 // window-local coords
        int dy = y0 - by + 8;
        int dz = z0 - bz + 8;
        // need [d, d+1] in window: dx,dy <= 30; dz <= 22
        bool ok = ((unsigned)dx <= 30u) & ((unsigned)dy <= 30u) & ((unsigned)dz <= 22u);

        float r;
        if (ok) {
            int idx = dz * 1024 + dy * 32 + dx;   // max 23518; +1057 = 24575 < 24576
            float c000 = __uint_as_float((unsigned)sm[idx       ] << 16);
            float c001 = __uint_as_float((unsigned)sm[idx + 1   ] << 16);
            float c010 = __uint_as_float((unsigned)sm[idx + 32  ] << 16);
            float c011 = __uint_as_float((unsigned)sm[idx + 33  ] << 16);
            float c100 = __uint_as_float((unsigned)sm[idx + 1024] << 16);
            float c101 = __uint_as_float((unsigned)sm[idx + 1025] << 16);
            float c110 = __uint_as_float((unsigned)sm[idx + 1056] << 16);
            float c111 = __uint_as_float((unsigned)sm[idx + 1057] << 16);
            float r00 = fmaf(wx, c001 - c000, c000);
            float r01 = fmaf(wx, c011 - c010, c010);
            float r10 = fmaf(wx, c101 - c100, c100);
            float r11 = fmaf(wx, c111 - c110, c110);
            float r0  = fmaf(wy, r01 - r00, r00);
            float r1  = fmaf(wy, r11 - r10, r10);
            r = fmaf(wz, r1 - r0, r0);
        } else {
            // slow path (~2% of voxels): proven border-clamped f32 gather
            int y1 = min(y0 + 1, HH - 1);
            int z1 = min(z0 + 1, DD - 1);
            int xb = min(x0, WW - 2);
            bool xe = (x0 == WW - 1);
            F2 q00 = *(const F2*)(src + ((size_t)z0 * HH + y0) * WW + xb);
            F2 q01 = *(const F2*)(src + ((size_t)z0 * HH + y1) * WW + xb);
            F2 q10 = *(const F2*)(src + ((size_t)z1 * HH + y0) * WW + xb);
            F2 q11 = *(const F2*)(src + ((size_t)z1 * HH + y1) * WW + xb);
            float c000 = xe ? q00.b : q00.a, c001 = q00.b;
            float c010 = xe ? q01.b : q01.a, c011 = q01.b;
            float c100 = xe ? q10.b : q10.a, c101 = q10.b;
            float c110 = xe ? q11.b : q11.a, c111 = q11.b;
            float r00 = fmaf(wx, c001 - c000, c000);
            float r01 = fmaf(wx, c011 - c010, c010);
            float r10 = fmaf(wx, c101 - c100, c100);
            float r11 = fmaf(wx, c111 - c110, c110);
            float r0  = fmaf(wy, r01 - r00, r00);
            float r1  = fmaf(wy, r11 - r10, r10);
            r = fmaf(wz, r1 - r0, r0);
        }
        res[v] = r;
    }
    *(float4*)(out + gbase) = make_float4(res[0], res[1], res[2], res[3]);
}

extern "C" void kernel_launch(void* const* d_in, const int* in_sizes, int n_in,
                              void* d_out, int out_size, void* d_ws, size_t ws_size,
                              hipStream_t stream) {
    const float* src  = (const float*)d_in[0];   // [1,1,D,H,W]
    const float* flow = (const float*)d_in[1];   // [1,3,D,H,W]
    // d_in[2] identity grid: unused (recomputed); d_ws: unused (no prepass)
    float* out = (float*)d_out;

    warp_fused_kernel<<<2400, 512, 0, stream>>>(src, flow, out);
}

// Round 12
// 171.537 us; speedup vs baseline: 1.0412x; 1.0190x over previous
//
#include <hip/hip_runtime.h>

// Spatial transformer: trilinear warp of src by flow, border padding.
// D=160, H=192, W=160.  u = (idx + flow) * S/(S-1) - 0.5, clamp, trilinear.
//
// Lineage:
//   R5-R9 (global gather) and R10-R16 (LDS-staged: occupancy, slow-path,
//   cold-start, prefetch, fused-staging variants) converge 48.5-63us warp
//   with no counter >20% => structural latency floor; warp frozen at R13's
//   proven 48.7us structure.
//   Ledger: total = warp + pack + ~111-116us fixed. R13 best (172.8).
//   R16 single-kernel fusion: -5us launch overhead but +15us staging = net +2.
// R17: R13 verbatim, pack rewritten: interior chunks (q in [1,20]) are
//   clamp-free -> 2x float4 vector loads (was 8 scalar clamped loads);
//   edge chunks (q=0, q>=21) are fully-clamped SPLATS of srow[0]/srow[159]
//   -> 1 scalar load; rounding via v_cvt_pk_bf16_f32 (RNE == bf16_rn,
//   verified R16 same absmax).

#define DD 160
#define HH 192
#define WW 160
#define DHW (DD * HH * WW)
#define PW 192                                   /* padded width: slot s <-> gx = clamp(s-8) */
#define NROWS (DD * HH)                          /* 30720 */
#define WS_NEEDED ((size_t)NROWS * PW * 2)       /* 11,796,480 B */

// ---------------- prepass: padded bf16 volume (vectorized) ----------------
// bsrc[row][s] = bf16(src[row][clamp(s-8, 0, WW-1)]), s in [0,192)
__global__ __launch_bounds__(256) void pack_bf16_kernel(
    const float* __restrict__ src, unsigned short* __restrict__ bsrc)
{
    int t = blockIdx.x * 256 + (int)threadIdx.x;  // 737,280 threads = 2880 blocks
    int q = t % (PW / 8);                          // 24 chunks of 8 slots
    int row = t / (PW / 8);                        // [0, 30720)
    const float* srow = src + (size_t)row * WW;
    int j0 = q * 8;                                // slots [j0, j0+8) <-> gx [j0-8, j0-1]

    unsigned int e[4];
    if (q >= 1 && q <= 20) {
        // interior: gx in [0, 159], 32B-aligned
        const float4 a = *(const float4*)(srow + j0 - 8);
        const float4 c = *(const float4*)(srow + j0 - 4);
        asm("v_cvt_pk_bf16_f32 %0, %1, %2" : "=v"(e[0]) : "v"(a.x), "v"(a.y));
        asm("v_cvt_pk_bf16_f32 %0, %1, %2" : "=v"(e[1]) : "v"(a.z), "v"(a.w));
        asm("v_cvt_pk_bf16_f32 %0, %1, %2" : "=v"(e[2]) : "v"(c.x), "v"(c.y));
        asm("v_cvt_pk_bf16_f32 %0, %1, %2" : "=v"(e[3]) : "v"(c.z), "v"(c.w));
    } else {
        // edge: ALL 8 gx clamp to the same border texel (q=0 -> 0; q>=21 -> 159)
        float v = (q == 0) ? srow[0] : srow[WW - 1];
        unsigned int p;
        asm("v_cvt_pk_bf16_f32 %0, %1, %2" : "=v"(p) : "v"(v), "v"(v));
        e[0] = p; e[1] = p; e[2] = p; e[3] = p;
    }
    *(uint4*)(bsrc + (size_t)row * PW + j0) = make_uint4(e[0], e[1], e[2], e[3]);
}

// ---------------- main: LDS-staged trilinear, 48KB window (R13 verbatim) ----------------
struct __align__(4) F2 { float a, b; };

__global__ __launch_bounds__(512) void warp_lds_kernel(
    const unsigned short* __restrict__ bsrc,
    const float* __restrict__ src,
    const float* __restrict__ flow,
    float* __restrict__ out)
{
    __shared__ unsigned short sm[24 * 32 * 32];   // 48 KB: [dz<24][dy<32][dx<32]

    // grid 2400 = 10 x 12 x 20; XCD k gets contiguous nb range.
    int b = blockIdx.x;
    int nb = (b & 7) * 300 + (b >> 3);
    int txq = nb % 10;
    int rem = nb / 10;
    int tyq = rem % 12;
    int tzq = rem / 12;                           // [0,20)
    int bx = txq * 16, by = tyq * 16, bz = tzq * 8;

    int t = (int)threadIdx.x;                     // 512 threads = 8 waves
    int lane = t & 63;
    int wave = t >> 6;

    // ---- stage window: z in [bz-8, bz+16), y in [by-8, by+24), x slots [bx,bx+32) ----
    #pragma unroll
    for (int k = 0; k < 6; ++k) {
        int row = (wave * 6 + k) * 16 + (lane >> 2);   // 0..767 = zz*32+yy
        int zz = row >> 5;                              // [0,24)
        int yy = row & 31;
        int gz = min(max(bz - 8 + zz, 0), DD - 1);
        int gy = min(max(by - 8 + yy, 0), HH - 1);
        const uint4 vv = *(const uint4*)(bsrc + (size_t)(gz * HH + gy) * PW + bx + (lane & 3) * 8);
        *(uint4*)&sm[row * 32 + (lane & 3) * 8] = vv;
    }

    // ---- flow for this thread's 4 voxels, issued BEFORE the barrier ----
    int vi = t * 4;                               // [0,2048) = 16x16x8 tile
    int tx = vi & 15;
    int ty = (vi >> 4) & 15;
    int tz = vi >> 8;                             // [0,8)
    int gw = bx + tx, gh = by + ty, gd = bz + tz;
    int gbase = (gd * HH + gh) * WW + gw;

    const float4 fz4 = *(const float4*)(flow + gbase);            // -> D/z
    const float4 fy4 = *(const float4*)(flow + DHW + gbase);      // -> H/y
    const float4 fx4 = *(const float4*)(flow + 2 * DHW + gbase);  // -> W/x
    const float* pz = (const float*)&fz4;
    const float* py = (const float*)&fy4;
    const float* px = (const float*)&fx4;

    __syncthreads();

    const float SX = (float)WW / (float)(WW - 1);
    const float SY = (float)HH / (float)(HH - 1);
    const float SZ = (float)DD / (float)(DD - 1);

    float res[4];
    #pragma unroll
    for (int v = 0; v < 4; ++v) {
        float ux = fmaf((float)(gw + v) + px[v], SX, -0.5f);
        float uy = fmaf((float)gh + py[v],       SY, -0.5f);
        float uz = fmaf((float)gd + pz[v],       SZ, -0.5f);
        ux = fminf(fmaxf(ux, 0.0f), (float)(WW - 1));
        uy = fminf(fmaxf(uy, 0.0f), (float)(HH - 1));
        uz = fminf(fmaxf(uz, 0.0f), (float)(DD - 1));
        float x0f = floorf(ux), y0f = floorf(uy), z0f = floorf(uz);
        float wx = ux - x0f, wy = uy - y0f, wz = uz - z0f;
        int x0 = (int)x0f, y0 = (int)y0f, z0 = (int)z0f;

        int dx = x0 - bx + 8;                 // window-local coords
        int dy = y0 - by + 8;
        int dz = z0 - bz + 8;
        // need [d, d+1] in window: dx,dy <= 30; dz <= 22
        bool ok = ((unsigned)dx <= 30u) & ((unsigned)dy <= 30u) & ((unsigned)dz <= 22u);

        float r;
        if (ok) {
            int idx = dz * 1024 + dy * 32 + dx;   // max 23518; +1057 = 24575 < 24576
            float c000 = __uint_as_float((unsigned)sm[idx       ] << 16);
            float c001 = __uint_as_float((unsigned)sm[idx + 1   ] << 16);
            float c010 = __uint_as_float((unsigned)sm[idx + 32  ] << 16);
            float c011 = __uint_as_float((unsigned)sm[idx + 33  ] << 16);
            float c100 = __uint_as_float((unsigned)sm[idx + 1024] << 16);
            float c101 = __uint_as_float((unsigned)sm[idx + 1025] << 16);
            float c110 = __uint_as_float((unsigned)sm[idx + 1056] << 16);
            float c111 = __uint_as_float((unsigned)sm[idx + 1057] << 16);
            float r00 = fmaf(wx, c001 - c000, c000);
            float r01 = fmaf(wx, c011 - c010, c010);
            float r10 = fmaf(wx, c101 - c100, c100);
            float r11 = fmaf(wx, c111 - c110, c110);
            float r0  = fmaf(wy, r01 - r00, r00);
            float r1  = fmaf(wy, r11 - r10, r10);
            r = fmaf(wz, r1 - r0, r0);
        } else {
            // slow path (~2% of voxels): proven border-clamped f32 gather
            int y1 = min(y0 + 1, HH - 1);
            int z1 = min(z0 + 1, DD - 1);
            int xb = min(x0, WW - 2);
            bool xe = (x0 == WW - 1);
            F2 q00 = *(const F2*)(src + ((size_t)z0 * HH + y0) * WW + xb);
            F2 q01 = *(const F2*)(src + ((size_t)z0 * HH + y1) * WW + xb);
            F2 q10 = *(const F2*)(src + ((size_t)z1 * HH + y0) * WW + xb);
            F2 q11 = *(const F2*)(src + ((size_t)z1 * HH + y1) * WW + xb);
            float c000 = xe ? q00.b : q00.a, c001 = q00.b;
            float c010 = xe ? q01.b : q01.a, c011 = q01.b;
            float c100 = xe ? q10.b : q10.a, c101 = q10.b;
            float c110 = xe ? q11.b : q11.a, c111 = q11.b;
            float r00 = fmaf(wx, c001 - c000, c000);
            float r01 = fmaf(wx, c011 - c010, c010);
            float r10 = fmaf(wx, c101 - c100, c100);
            float r11 = fmaf(wx, c111 - c110, c110);
            float r0  = fmaf(wy, r01 - r00, r00);
            float r1  = fmaf(wy, r11 - r10, r10);
            r = fmaf(wz, r1 - r0, r0);
        }
        res[v] = r;
    }
    *(float4*)(out + gbase) = make_float4(res[0], res[1], res[2], res[3]);
}

// ---------------- fallback (proven R2 kernel) if ws too small ----------------
__global__ __launch_bounds__(256) void warp_direct_kernel(
    const float* __restrict__ src,
    const float* __restrict__ flow,
    float* __restrict__ out)
{
    int b = blockIdx.x;
    int nb = (b & 7) * 600 + (b >> 3);
    int base = (nb * 256 + (int)threadIdx.x) * 4;

    int w = base % WW;
    int tmp = base / WW;
    int h = tmp % HH;
    int d = tmp / HH;

    const float4 f0  = *(const float4*)(flow + base);
    const float4 f1  = *(const float4*)(flow + DHW + base);
    const float4 f2v = *(const float4*)(flow + 2 * DHW + base);
    const float* f0p = (const float*)&f0;
    const float* f1p = (const float*)&f1;
    const float* f2p = (const float*)&f2v;

    const float SX = (float)WW / (float)(WW - 1);
    const float SY = (float)HH / (float)(HH - 1);
    const float SZ = (float)DD / (float)(DD - 1);

    float res[4];
    #pragma unroll
    for (int v = 0; v < 4; ++v) {
        float ux = fmaf((float)(w + v) + f2p[v], SX, -0.5f);
        float uy = fmaf((float)h + f1p[v],       SY, -0.5f);
        float uz = fmaf((float)d + f0p[v],       SZ, -0.5f);
        ux = fminf(fmaxf(ux, 0.0f), (float)(WW - 1));
        uy = fminf(fmaxf(uy, 0.0f), (float)(HH - 1));
        uz = fminf(fmaxf(uz, 0.0f), (float)(DD - 1));
        float x0f = floorf(ux), y0f = floorf(uy), z0f = floorf(uz);
        float fx = ux - x0f, fy = uy - y0f, fz = uz - z0f;
        int x0 = (int)x0f, y0 = (int)y0f, z0 = (int)z0f;
        int y1 = min(y0 + 1, HH - 1);
        int z1 = min(z0 + 1, DD - 1);
        int xb = min(x0, WW - 2);
        bool xe = (x0 == WW - 1);
        F2 q00 = *(const F2*)(src + ((size_t)z0 * HH + y0) * WW + xb);
        F2 q01 = *(const F2*)(src + ((size_t)z0 * HH + y1) * WW + xb);
        F2 q10 = *(const F2*)(src + ((size_t)z1 * HH + y0) * WW + xb);
        F2 q11 = *(const F2*)(src + ((size_t)z1 * HH + y1) * WW + xb);
        float c000 = xe ? q00.b : q00.a, c001 = q00.b;
        float c010 = xe ? q01.b : q01.a, c011 = q01.b;
        float c100 = xe ? q10.b : q10.a, c101 = q10.b;
        float c110 = xe ? q11.b : q11.a, c111 = q11.b;
        float r00 = fmaf(fx, c001 - c000, c000);
        float r01 = fmaf(fx, c011 - c010, c010);
        float r10 = fmaf(fx, c101 - c100, c100);
        float r11 = fmaf(fx, c111 - c110, c110);
        float r0  = fmaf(fy, r01 - r00, r00);
        float r1  = fmaf(fy, r11 - r10, r10);
        res[v]    = fmaf(fz, r1 - r0, r0);
    }
    *(float4*)(out + base) = make_float4(res[0], res[1], res[2], res[3]);
}

extern "C" void kernel_launch(void* const* d_in, const int* in_sizes, int n_in,
                              void* d_out, int out_size, void* d_ws, size_t ws_size,
                              hipStream_t stream) {
    const float* src  = (const float*)d_in[0];   // [1,1,D,H,W]
    const float* flow = (const float*)d_in[1];   // [1,3,D,H,W]
    // d_in[2] identity grid: unused (recomputed)
    float* out = (float*)d_out;

    if (ws_size >= WS_NEEDED) {
        unsigned short* bsrc = (unsigned short*)d_ws;
        pack_bf16_kernel<<<(NROWS * (PW / 8)) / 256, 256, 0, stream>>>(src, bsrc);
        warp_lds_kernel<<<2400, 512, 0, stream>>>(bsrc, src, flow, out);
    } else {
        warp_direct_kernel<<<DHW / 4 / 256, 256, 0, stream>>>(src, flow, out);
    }
}